// Round 8
// baseline (5674.959 us; speedup 1.0000x reference)
//
#include <hip/hip_runtime.h>
#include <cstdint>
#include <cstddef>

#define B_ 4
#define T_ 24
#define N_ 512

// gate nonlinearities: evaluate in f64, round once to f32 (R4-proven numerics)
__device__ __forceinline__ float fsig(float x)  { return (float)(1.0 / (1.0 + exp(-(double)x))); }
__device__ __forceinline__ float ftanh(float x) { return (float)tanh((double)x); }

// 16-slot XOR swizzle for [F][64] LDS tiles
__device__ __forceinline__ int swz16(int f) { return (((f & 15) ^ ((f >> 4) & 15)) << 2); }

// ================= PRECOMPUTE =================

// xp = relu(x @ fc_w + fc_b), stored feature-major xpT[bt][f][node]
__global__ __launch_bounds__(256) void xpT_kernel(const float* __restrict__ x,
                                                  const float* __restrict__ fc_w,
                                                  const float* __restrict__ fc_b,
                                                  float* __restrict__ xpT) {
    __shared__ __align__(16) float sX[64 * 68];
    __shared__ __align__(16) float sW[64 * 64];
    __shared__ float sB[64];
    const int bt = blockIdx.y;
    const int n0 = blockIdx.x * 64;
    const int tid = threadIdx.x;
    for (int i = tid * 4; i < 4096; i += 1024)
        *(float4*)&sW[i] = *(const float4*)&fc_w[i];
    if (tid < 64) sB[tid] = fc_b[tid];
    {
        int r = tid >> 2, kq = (tid & 3) * 16;
        const float* p = x + ((size_t)bt * N_ + n0 + r) * 64 + kq;
        #pragma unroll
        for (int j = 0; j < 4; ++j)
            *(float4*)&sX[r * 68 + kq + j * 4] = *(const float4*)(p + j * 4);
    }
    __syncthreads();
    const int f = tid & 63, ng = tid >> 6;
    float d[16];
    #pragma unroll
    for (int j = 0; j < 16; ++j) d[j] = 0.f;
    for (int k = 0; k < 64; ++k) {
        float w = sW[k * 64 + f];
        #pragma unroll
        for (int j = 0; j < 16; ++j)
            d[j] = fmaf(sX[(ng * 16 + j) * 68 + k], w, d[j]);
    }
    const float bias = sB[f];
    float* o = xpT + ((size_t)bt * 64 + f) * N_ + n0 + ng * 16;
    #pragma unroll
    for (int j = 0; j < 16; ++j)
        o[j] = fmaxf(__fadd_rn(d[j], bias), 0.f);
}

// UX[bt][node][64] = (A_bt @ xp_bt) — recurrence-independent, fully parallel
__global__ __launch_bounds__(256) void ux_kernel(const float* __restrict__ e,
                                                 const float* __restrict__ xpT,
                                                 float* __restrict__ UX) {
    __shared__ __align__(16) float sA[8 * N_];
    __shared__ __align__(16) float sVT[2 * 4096];
    const int bt = blockIdx.y;
    const int m0 = blockIdx.x * 8;
    const int tid = threadIdx.x;
    {
        const int r = tid >> 5, seg = (tid & 31) * 16;
        const float* src = e + ((size_t)bt * N_ + m0 + r) * N_ + seg;
        float* dst = sA + r * N_ + seg;
        #pragma unroll
        for (int j = 0; j < 4; ++j)
            *(float4*)(dst + j * 4) = *(const float4*)(src + j * 4);
    }
    const float* s0 = xpT + (size_t)bt * 64 * N_;
    auto stage64 = [&](float* dst, int k0) {
        const int f = tid >> 2, q = tid & 3;
        const int sw = swz16(f);
        const float* src = s0 + (size_t)f * N_ + k0;
        #pragma unroll
        for (int j = 0; j < 4; ++j) {
            int k = q * 16 + j * 4;
            *(float4*)&dst[f * 64 + (k ^ sw)] = *(const float4*)(src + k);
        }
    };
    stage64(sVT, 0);
    __syncthreads();
    const int r = tid >> 5, cgi = tid & 31;
    const int c0 = 2 * cgi, c1 = c0 + 1;
    const int sw0 = swz16(c0), sw1 = swz16(c1);
    float a0 = 0.f, a1 = 0.f;
    for (int kb = 0; kb < 8; ++kb) {
        const float* cur = sVT + (kb & 1) * 4096;
        if (kb < 7) stage64(sVT + ((kb + 1) & 1) * 4096, (kb + 1) * 64);
        const float* A0 = sA + r * N_ + kb * 64;
        const float* V0 = cur + c0 * 64;
        const float* V1 = cur + c1 * 64;
        #pragma unroll
        for (int kg = 0; kg < 16; ++kg) {
            int k = kg * 4;
            float4 x = *(const float4*)(A0 + k);
            float4 v0 = *(const float4*)(V0 + (k ^ sw0));
            float4 v1 = *(const float4*)(V1 + (k ^ sw1));
            a0 = fmaf(x.x, v0.x, a0); a0 = fmaf(x.y, v0.y, a0);
            a0 = fmaf(x.z, v0.z, a0); a0 = fmaf(x.w, v0.w, a0);
            a1 = fmaf(x.x, v1.x, a1); a1 = fmaf(x.y, v1.y, a1);
            a1 = fmaf(x.z, v1.z, a1); a1 = fmaf(x.w, v1.w, a1);
        }
        __syncthreads();
    }
    *(float2*)&UX[((size_t)bt * N_ + m0 + r) * 64 + c0] = make_float2(a0, a1);
}

// ================= COOPERATIVE SCAN (BM=16, 128 blocks, 512 threads) =================

// C = A @ V (16 x F): 2-deep register prefetch + 3-buffer LDS pipeline.
// Strict ascending-k fmaf chain per output (numerics identical to R4/R7).
template <int F>
__device__ __forceinline__ void conv16(const float* __restrict__ sA,
                                       float* __restrict__ sP,   // 3 x 8192 floats
                                       float* __restrict__ sC,   // [16][132]
                                       const float* __restrict__ s0,
                                       const float* __restrict__ s1,
                                       int tid) {
    constexpr int RPT = (F == 128) ? 4 : 2;   // rows (outputs) per thread
    constexpr int LPT = (F == 128) ? 4 : 2;   // float4 loads per thread per tile
    const int c = tid & (F - 1);
    const int rg0 = (F == 128) ? (tid >> 7) : (tid >> 6);
    const int swc = swz16(c);

    float4 ra[LPT], rb[LPT];

    auto issue = [&](float4* r, int t) {
        if constexpr (F == 128) {
            const int f = tid >> 2, q = tid & 3;
            const float* src = ((f < 64) ? (s0 + (size_t)f * N_)
                                         : (s1 + (size_t)(f - 64) * N_)) + t * 64 + q * 16;
            #pragma unroll
            for (int j = 0; j < 4; ++j) r[j] = *(const float4*)(src + j * 4);
        } else {
            const int f = tid >> 3, o = tid & 7;
            const float* src = s0 + (size_t)f * N_ + t * 64 + o * 8;
            #pragma unroll
            for (int j = 0; j < 2; ++j) r[j] = *(const float4*)(src + j * 4);
        }
    };
    auto wlds = [&](float* buf, float4* r) {
        if constexpr (F == 128) {
            const int f = tid >> 2, q = tid & 3;
            const int sw = swz16(f);
            #pragma unroll
            for (int j = 0; j < 4; ++j)
                *(float4*)&buf[f * 64 + ((q * 16 + j * 4) ^ sw)] = r[j];
        } else {
            const int f = tid >> 3, o = tid & 7;
            const int sw = swz16(f);
            #pragma unroll
            for (int j = 0; j < 2; ++j)
                *(float4*)&buf[f * 64 + ((o * 8 + j * 4) ^ sw)] = r[j];
        }
    };

    float acc[RPT];
    #pragma unroll
    for (int i = 0; i < RPT; ++i) acc[i] = 0.f;

    auto comp = [&](const float* buf, int kt) {
        #pragma unroll
        for (int kg = 0; kg < 16; ++kg) {
            const int k = kg * 4;
            float4 v = *(const float4*)&buf[c * 64 + (k ^ swc)];
            #pragma unroll
            for (int i = 0; i < RPT; ++i) {
                float4 x = *(const float4*)&sA[(rg0 * RPT + i) * 512 + kt * 64 + k];
                acc[i] = fmaf(x.x, v.x, acc[i]);
                acc[i] = fmaf(x.y, v.y, acc[i]);
                acc[i] = fmaf(x.z, v.z, acc[i]);
                acc[i] = fmaf(x.w, v.w, acc[i]);
            }
        }
    };

    issue(ra, 0);
    issue(rb, 1);
    wlds(sP, ra);            // tile 0 -> buf 0
    __syncthreads();

    #pragma unroll
    for (int kb = 0; kb < 8; kb += 2) {
        // even sub-step: compute tile kb
        if (kb + 2 < 8) issue(ra, kb + 2);
        wlds(sP + ((kb + 1) % 3) * 8192, rb);       // tile kb+1 -> buf (kb+1)%3
        comp(sP + (kb % 3) * 8192, kb);
        __syncthreads();
        // odd sub-step: compute tile kb+1
        if (kb + 3 < 8) issue(rb, kb + 3);
        if (kb + 2 < 8) wlds(sP + ((kb + 2) % 3) * 8192, ra);
        comp(sP + ((kb + 1) % 3) * 8192, kb + 1);
        __syncthreads();
    }

    #pragma unroll
    for (int i = 0; i < RPT; ++i)
        sC[(rg0 * RPT + i) * 132 + c] = acc[i];
    __syncthreads();
}

// per-batch monotonic barrier (32 blocks), device-scope atomics + fences
__device__ __forceinline__ void batch_barrier(unsigned* __restrict__ cnt,
                                              unsigned target, int tid) {
    __syncthreads();
    if (tid == 0) {
        __threadfence();
        __hip_atomic_fetch_add(cnt, 1u, __ATOMIC_RELEASE, __HIP_MEMORY_SCOPE_AGENT);
        while (__hip_atomic_load(cnt, __ATOMIC_ACQUIRE, __HIP_MEMORY_SCOPE_AGENT) < target)
            __builtin_amdgcn_s_sleep(1);
        __threadfence();
    }
    __syncthreads();
}

__global__ __launch_bounds__(512, 1) void egcn_kernel(
    const float* __restrict__ e, const float* __restrict__ UX,
    const float* __restrict__ Wz1, const float* __restrict__ Wz2,
    const float* __restrict__ Wr1, const float* __restrict__ Wr2,
    const float* __restrict__ Wc1, const float* __restrict__ Wc2,
    float* __restrict__ hT, float* __restrict__ hzT, float* __restrict__ hrT,
    float* __restrict__ rhT, float* __restrict__ hcT,
    unsigned* __restrict__ bars, float* __restrict__ out) {
    __shared__ __align__(16) float sA[16 * 512];    // 32 KB
    __shared__ __align__(16) float sP[3 * 8192];    // 96 KB (3-buffer pipeline)
    __shared__ __align__(16) float sC[16 * 132];
    __shared__ __align__(16) float sUX[16 * 68];
    __shared__ __align__(16) float sZb[16 * 68];

    const int tid = threadIdx.x;
    const int bid = blockIdx.x;
    // XCD-affinity heuristic: batch b -> XCD pair {2b,2b+1} (bid%8 round-robin assumption;
    // correctness does NOT depend on it — agent-scope barrier handles any placement)
    const int xcd = bid & 7;
    const int b = xcd >> 1;
    const int slot = ((xcd & 1) << 4) | (bid >> 3);   // 0..31
    const int m0 = slot * 16;
    unsigned* cnt = bars + (size_t)b * 64;
    unsigned gen = 0;

    const float* hTb = hT + (size_t)b * 64 * N_;
    float* hzTb = hzT + (size_t)b * 64 * N_;
    float* hrTb = hrT + (size_t)b * 64 * N_;
    float* rhTb = rhT + (size_t)b * 64 * N_;
    float* hcTb = hcT + (size_t)b * 64 * N_;

    for (int t = 0; t < T_; ++t) {
        const int bt = b * T_ + t;
        {   // stage A rows [16][512] once per timestep
            const int r = tid >> 5, seg = (tid & 31) * 16;
            const float* src = e + ((size_t)bt * N_ + m0 + r) * N_ + seg;
            float* dst = sA + r * 512 + seg;
            #pragma unroll
            for (int j = 0; j < 4; ++j)
                *(float4*)(dst + j * 4) = *(const float4*)(src + j * 4);
        }
        if (tid < 256) {    // stage UX tile [16][64] (= A@xt rows, precomputed)
            const int n = tid >> 4, q = (tid & 15) * 4;
            *(float4*)&sUX[n * 68 + q] =
                *(const float4*)&UX[((size_t)bt * N_ + m0 + n) * 64 + q];
        }
        // (first __syncthreads inside conv16 orders sA/sUX writes before reads)

        // ---- P1: C = A@h; hz = relu([UX|C]@Wz1); hr = relu([UX|C]@Wr1) ----
        conv16<64>(sA, sP, sC, hTb, nullptr, tid);
        {
            const int sel = tid >> 8, f = tid & 63, ng = (tid >> 6) & 3, n0 = ng * 4;
            const float* W = sel ? Wr1 : Wz1;
            const float* U0 = sUX + (n0 + 0) * 68;
            const float* U1 = sUX + (n0 + 1) * 68;
            const float* U2 = sUX + (n0 + 2) * 68;
            const float* U3 = sUX + (n0 + 3) * 68;
            const float* C0 = sC + (n0 + 0) * 132;
            const float* C1 = sC + (n0 + 1) * 132;
            const float* C2 = sC + (n0 + 2) * 132;
            const float* C3 = sC + (n0 + 3) * 132;
            float d0 = 0.f, d1 = 0.f, d2 = 0.f, d3 = 0.f;
            #pragma unroll 4
            for (int k = 0; k < 64; ++k) {
                float w = W[k * 64 + f];
                d0 = fmaf(U0[k], w, d0); d1 = fmaf(U1[k], w, d1);
                d2 = fmaf(U2[k], w, d2); d3 = fmaf(U3[k], w, d3);
            }
            #pragma unroll 4
            for (int k = 0; k < 64; ++k) {
                float w = W[(64 + k) * 64 + f];
                d0 = fmaf(C0[k], w, d0); d1 = fmaf(C1[k], w, d1);
                d2 = fmaf(C2[k], w, d2); d3 = fmaf(C3[k], w, d3);
            }
            float* dstT = sel ? hrTb : hzTb;
            *(float4*)(dstT + (size_t)f * N_ + m0 + n0) =
                make_float4(fmaxf(d0, 0.f), fmaxf(d1, 0.f), fmaxf(d2, 0.f), fmaxf(d3, 0.f));
        }
        batch_barrier(cnt, (++gen) * 32, tid);

        // ---- P2: C = A@[hz|hr]; z -> LDS; rh = sig(.)*h -> global ----
        conv16<128>(sA, sP, sC, hzTb, hrTb, tid);
        {
            const int sel = tid >> 8, f = tid & 63, ng = (tid >> 6) & 3, n0 = ng * 4;
            const float* W = sel ? Wr2 : Wz2;
            const float* C0 = sC + (n0 + 0) * 132 + sel * 64;
            const float* C1 = sC + (n0 + 1) * 132 + sel * 64;
            const float* C2 = sC + (n0 + 2) * 132 + sel * 64;
            const float* C3 = sC + (n0 + 3) * 132 + sel * 64;
            float d0 = 0.f, d1 = 0.f, d2 = 0.f, d3 = 0.f;
            #pragma unroll 4
            for (int k = 0; k < 64; ++k) {
                float w = W[k * 64 + f];
                d0 = fmaf(C0[k], w, d0); d1 = fmaf(C1[k], w, d1);
                d2 = fmaf(C2[k], w, d2); d3 = fmaf(C3[k], w, d3);
            }
            if (!sel) {
                sZb[(n0 + 0) * 68 + f] = fsig(d0);
                sZb[(n0 + 1) * 68 + f] = fsig(d1);
                sZb[(n0 + 2) * 68 + f] = fsig(d2);
                sZb[(n0 + 3) * 68 + f] = fsig(d3);
            } else {
                float4 h4 = *(const float4*)(hTb + (size_t)f * N_ + m0 + n0);
                *(float4*)(rhTb + (size_t)f * N_ + m0 + n0) =
                    make_float4(__fmul_rn(fsig(d0), h4.x), __fmul_rn(fsig(d1), h4.y),
                                __fmul_rn(fsig(d2), h4.z), __fmul_rn(fsig(d3), h4.w));
            }
        }
        batch_barrier(cnt, (++gen) * 32, tid);

        // ---- P3: C = A@rh; hc = relu(UX@Wc1_top + C@Wc1_bot) ----
        conv16<64>(sA, sP, sC, rhTb, nullptr, tid);
        {
            const int f = tid & 63, ng = tid >> 6, n0 = ng * 2;
            const float* U0 = sUX + (n0 + 0) * 68;
            const float* U1 = sUX + (n0 + 1) * 68;
            const float* C0 = sC + (n0 + 0) * 132;
            const float* C1 = sC + (n0 + 1) * 132;
            float d0 = 0.f, d1 = 0.f;
            #pragma unroll 4
            for (int k = 0; k < 64; ++k) {
                float w = Wc1[k * 64 + f];
                d0 = fmaf(U0[k], w, d0); d1 = fmaf(U1[k], w, d1);
            }
            #pragma unroll 4
            for (int k = 0; k < 64; ++k) {
                float w = Wc1[(64 + k) * 64 + f];
                d0 = fmaf(C0[k], w, d0); d1 = fmaf(C1[k], w, d1);
            }
            *(float2*)(hcTb + (size_t)f * N_ + m0 + n0) =
                make_float2(fmaxf(d0, 0.f), fmaxf(d1, 0.f));
        }
        batch_barrier(cnt, (++gen) * 32, tid);

        // ---- P4: C = A@hc; c = tanh(C@Wc2); hn = z*h + (1-z)*c ----
        conv16<64>(sA, sP, sC, hcTb, nullptr, tid);
        {
            const int f = tid & 63, ng = tid >> 6, n0 = ng * 2;
            const float* C0 = sC + (n0 + 0) * 132;
            const float* C1 = sC + (n0 + 1) * 132;
            float d0 = 0.f, d1 = 0.f;
            #pragma unroll 4
            for (int k = 0; k < 64; ++k) {
                float w = Wc2[k * 64 + f];
                d0 = fmaf(C0[k], w, d0); d1 = fmaf(C1[k], w, d1);
            }
            float c0 = ftanh(d0), c1 = ftanh(d1);
            float z0 = sZb[(n0 + 0) * 68 + f], z1 = sZb[(n0 + 1) * 68 + f];
            float* hp = hT + ((size_t)b * 64 + f) * N_ + m0 + n0;
            float h0 = hp[0], h1 = hp[1];
            float hn0 = __fadd_rn(__fmul_rn(z0, h0), __fmul_rn(__fsub_rn(1.f, z0), c0));
            float hn1 = __fadd_rn(__fmul_rn(z1, h1), __fmul_rn(__fsub_rn(1.f, z1), c1));
            hp[0] = hn0; hp[1] = hn1;
            out[((size_t)bt * N_ + m0 + n0) * 64 + f] = hn0;
            out[((size_t)bt * N_ + m0 + n0 + 1) * 64 + f] = hn1;
        }
        batch_barrier(cnt, (++gen) * 32, tid);
    }
}

// ================= FALLBACK PATH (R4, proven) =================

__global__ __launch_bounds__(256) void xp_row_kernel(const float* __restrict__ x,
                                                     const float* __restrict__ fc_w,
                                                     const float* __restrict__ fc_b,
                                                     float* __restrict__ xp) {
    __shared__ float sW[64 * 64];
    __shared__ float sB[64];
    __shared__ float sX[64 * 65];
    int bt = blockIdx.x;
    int tid = threadIdx.x;
    for (int i = tid; i < 4096; i += 256) sW[i] = fc_w[i];
    if (tid < 64) sB[tid] = fc_b[tid];
    const float* xb = x + (size_t)bt * N_ * 64;
    float* ob = xp + (size_t)bt * N_ * 64;
    for (int rt = 0; rt < 8; ++rt) {
        __syncthreads();
        {
            int r = tid >> 2, kq = (tid & 3) * 16;
            const float* p = xb + (size_t)(rt * 64 + r) * 64 + kq;
            #pragma unroll
            for (int i = 0; i < 4; ++i) {
                float4 d = *(const float4*)(p + i * 4);
                sX[r * 65 + kq + i * 4 + 0] = d.x;
                sX[r * 65 + kq + i * 4 + 1] = d.y;
                sX[r * 65 + kq + i * 4 + 2] = d.z;
                sX[r * 65 + kq + i * 4 + 3] = d.w;
            }
        }
        __syncthreads();
        int rg = tid >> 4;
        int c0 = (tid & 15) * 4;
        #pragma unroll
        for (int v = 0; v < 4; ++v) {
            int r = rg * 4 + v;
            float a0 = 0.f, a1 = 0.f, a2 = 0.f, a3 = 0.f;
            #pragma unroll 8
            for (int k = 0; k < 64; ++k) {
                float xv = sX[r * 65 + k];
                a0 = fmaf(xv, sW[k * 64 + c0 + 0], a0);
                a1 = fmaf(xv, sW[k * 64 + c0 + 1], a1);
                a2 = fmaf(xv, sW[k * 64 + c0 + 2], a2);
                a3 = fmaf(xv, sW[k * 64 + c0 + 3], a3);
            }
            a0 = __fadd_rn(a0, sB[c0 + 0]);
            a1 = __fadd_rn(a1, sB[c0 + 1]);
            a2 = __fadd_rn(a2, sB[c0 + 2]);
            a3 = __fadd_rn(a3, sB[c0 + 3]);
            *(float4*)&ob[(size_t)(rt * 64 + r) * 64 + c0] =
                make_float4(fmaxf(a0, 0.f), fmaxf(a1, 0.f), fmaxf(a2, 0.f), fmaxf(a3, 0.f));
        }
    }
}

template <int STAGE>
__global__ __launch_bounds__(256) void stage_kernel(
    const float* __restrict__ e, int t,
    const float* __restrict__ xp,
    const float* __restrict__ Wz1, const float* __restrict__ Wz2,
    const float* __restrict__ Wr1, const float* __restrict__ Wr2,
    const float* __restrict__ Wc1, const float* __restrict__ Wc2,
    float* __restrict__ hf, float* __restrict__ ux,
    float* __restrict__ hz, float* __restrict__ hr,
    float* __restrict__ zb, float* __restrict__ rh,
    float* __restrict__ hc, float* __restrict__ out)
{
    constexpr int F  = (STAGE <= 2) ? 128 : 64;
    constexpr int BM = 16;
    constexpr int SA = 68;
    constexpr int SC = F + 4;
    constexpr int CT = (F == 128) ? 2 : 1;
    constexpr int SMEM = BM * SA + F * SA + BM * SC;
    __shared__ __align__(16) float smem[SMEM];
    float* sA  = smem;
    float* sVT = smem + BM * SA;
    float* sC  = smem + BM * SA + F * SA;
    float* sW  = smem;

    const int b   = blockIdx.y;
    const int m0  = blockIdx.x * BM;
    const int tid = threadIdx.x;

    const float* Ab = e + ((size_t)(b * T_ + t) * N_ + m0) * N_;

    const float* v0;
    const float* v1 = nullptr;
    if (STAGE == 1)      { v0 = xp + (size_t)(b * T_ + t) * N_ * 64; v1 = hf + (size_t)b * N_ * 64; }
    else if (STAGE == 2) { v0 = hz + (size_t)b * N_ * 64;            v1 = hr + (size_t)b * N_ * 64; }
    else if (STAGE == 3) { v0 = rh + (size_t)b * N_ * 64; }
    else                 { v0 = hc + (size_t)b * N_ * 64; }

    const int r0 = (tid & 3) * 4;
    const int c0 = (tid >> 2) * CT;
    float acc[4][CT];
    #pragma unroll
    for (int ri = 0; ri < 4; ++ri)
        #pragma unroll
        for (int ci = 0; ci < CT; ++ci) acc[ri][ci] = 0.f;

    for (int kb = 0; kb < N_; kb += 64) {
        {
            int r = tid >> 4, kq = (tid & 15) * 4;
            int sw = ((r >> 2) & 3) << 2;
            *(float4*)&sA[r * SA + (kq ^ sw)] = *(const float4*)(Ab + (size_t)r * N_ + kb + kq);
        }
        {
            #pragma unroll
            for (int pp = 0; pp < (64 * F) / 1024; ++pp) {
                int idx = pp * 1024 + tid * 4;
                int k = idx / F;
                int f = idx % F;
                const float* src;
                if constexpr (F == 128)
                    src = (f < 64) ? (v0 + (size_t)(kb + k) * 64 + f)
                                   : (v1 + (size_t)(kb + k) * 64 + (f - 64));
                else
                    src = v0 + (size_t)(kb + k) * 64 + f;
                float4 d4 = *(const float4*)src;
                float dd[4] = {d4.x, d4.y, d4.z, d4.w};
                #pragma unroll
                for (int j = 0; j < 4; ++j) {
                    int ff = f + j;
                    int sw = (((ff >> 3) ^ (ff >> 5)) & 3) << 2;
                    sVT[ff * SA + (k ^ sw)] = dd[j];
                }
            }
        }
        __syncthreads();
        #pragma unroll 4
        for (int k = 0; k < 64; k += 4) {
            float4 a4[4], v4[CT];
            #pragma unroll
            for (int ri = 0; ri < 4; ++ri) {
                int r = r0 + ri;
                a4[ri] = *(const float4*)&sA[r * SA + (k ^ (((r >> 2) & 3) << 2))];
            }
            #pragma unroll
            for (int ci = 0; ci < CT; ++ci) {
                int f = c0 + ci;
                v4[ci] = *(const float4*)&sVT[f * SA + (k ^ ((((f >> 3) ^ (f >> 5)) & 3) << 2))];
            }
            #pragma unroll
            for (int ri = 0; ri < 4; ++ri)
                #pragma unroll
                for (int ci = 0; ci < CT; ++ci) {
                    acc[ri][ci] = fmaf(a4[ri].x, v4[ci].x, acc[ri][ci]);
                    acc[ri][ci] = fmaf(a4[ri].y, v4[ci].y, acc[ri][ci]);
                    acc[ri][ci] = fmaf(a4[ri].z, v4[ci].z, acc[ri][ci]);
                    acc[ri][ci] = fmaf(a4[ri].w, v4[ci].w, acc[ri][ci]);
                }
        }
        __syncthreads();
    }

    if (STAGE == 1 && c0 < 64) {
        #pragma unroll
        for (int ri = 0; ri < 4; ++ri)
            *(float2*)&ux[((size_t)b * N_ + m0 + r0 + ri) * 64 + c0] =
                make_float2(acc[ri][0], acc[ri][1]);
    }

    #pragma unroll
    for (int ri = 0; ri < 4; ++ri) {
        if constexpr (CT == 2)
            *(float2*)&sC[(r0 + ri) * SC + c0] = make_float2(acc[ri][0], acc[ri][1]);
        else
            sC[(r0 + ri) * SC + c0] = acc[ri][0];
    }
    __syncthreads();

    const int rr  = tid >> 4;
    const int cc0 = (tid & 15) * 4;
    const float* Crow = &sC[rr * SC];
    const size_t orow = ((size_t)b * N_ + m0 + rr) * 64 + cc0;

    auto stageW = [&](const float* W, int n) {
        for (int i = tid * 4; i < n; i += 1024)
            *(float4*)&sW[i] = *(const float4*)&W[i];
    };

    if constexpr (STAGE == 1) {
        stageW(Wz1, 128 * 64); __syncthreads();
        float d[4] = {0.f, 0.f, 0.f, 0.f};
        for (int k = 0; k < 128; ++k) {
            float cv = Crow[k];
            const float* w = &sW[k * 64 + cc0];
            d[0] = fmaf(cv, w[0], d[0]); d[1] = fmaf(cv, w[1], d[1]);
            d[2] = fmaf(cv, w[2], d[2]); d[3] = fmaf(cv, w[3], d[3]);
        }
        *(float4*)&hz[orow] = make_float4(fmaxf(d[0], 0.f), fmaxf(d[1], 0.f),
                                          fmaxf(d[2], 0.f), fmaxf(d[3], 0.f));
        __syncthreads();
        stageW(Wr1, 128 * 64); __syncthreads();
        float g[4] = {0.f, 0.f, 0.f, 0.f};
        for (int k = 0; k < 128; ++k) {
            float cv = Crow[k];
            const float* w = &sW[k * 64 + cc0];
            g[0] = fmaf(cv, w[0], g[0]); g[1] = fmaf(cv, w[1], g[1]);
            g[2] = fmaf(cv, w[2], g[2]); g[3] = fmaf(cv, w[3], g[3]);
        }
        *(float4*)&hr[orow] = make_float4(fmaxf(g[0], 0.f), fmaxf(g[1], 0.f),
                                          fmaxf(g[2], 0.f), fmaxf(g[3], 0.f));
    }

    if constexpr (STAGE == 2) {
        stageW(Wz2, 64 * 64); __syncthreads();
        float d[4] = {0.f, 0.f, 0.f, 0.f};
        for (int k = 0; k < 64; ++k) {
            float cv = Crow[k];
            const float* w = &sW[k * 64 + cc0];
            d[0] = fmaf(cv, w[0], d[0]); d[1] = fmaf(cv, w[1], d[1]);
            d[2] = fmaf(cv, w[2], d[2]); d[3] = fmaf(cv, w[3], d[3]);
        }
        *(float4*)&zb[orow] = make_float4(fsig(d[0]), fsig(d[1]), fsig(d[2]), fsig(d[3]));
        __syncthreads();
        stageW(Wr2, 64 * 64); __syncthreads();
        float g[4] = {0.f, 0.f, 0.f, 0.f};
        for (int k = 0; k < 64; ++k) {
            float cv = Crow[64 + k];
            const float* w = &sW[k * 64 + cc0];
            g[0] = fmaf(cv, w[0], g[0]); g[1] = fmaf(cv, w[1], g[1]);
            g[2] = fmaf(cv, w[2], g[2]); g[3] = fmaf(cv, w[3], g[3]);
        }
        float4 hv = *(const float4*)&hf[orow];
        *(float4*)&rh[orow] = make_float4(__fmul_rn(fsig(g[0]), hv.x),
                                          __fmul_rn(fsig(g[1]), hv.y),
                                          __fmul_rn(fsig(g[2]), hv.z),
                                          __fmul_rn(fsig(g[3]), hv.w));
    }

    if constexpr (STAGE == 3) {
        stageW(Wc1, 64 * 64); __syncthreads();
        float d[4] = {0.f, 0.f, 0.f, 0.f};
        const float* uxr = &ux[((size_t)b * N_ + m0 + rr) * 64];
        for (int k = 0; k < 64; ++k) {
            float cv = uxr[k];
            const float* w = &sW[k * 64 + cc0];
            d[0] = fmaf(cv, w[0], d[0]); d[1] = fmaf(cv, w[1], d[1]);
            d[2] = fmaf(cv, w[2], d[2]); d[3] = fmaf(cv, w[3], d[3]);
        }
        __syncthreads();
        stageW(Wc1 + 64 * 64, 64 * 64); __syncthreads();
        for (int k = 0; k < 64; ++k) {
            float cv = Crow[k];
            const float* w = &sW[k * 64 + cc0];
            d[0] = fmaf(cv, w[0], d[0]); d[1] = fmaf(cv, w[1], d[1]);
            d[2] = fmaf(cv, w[2], d[2]); d[3] = fmaf(cv, w[3], d[3]);
        }
        *(float4*)&hc[orow] = make_float4(fmaxf(d[0], 0.f), fmaxf(d[1], 0.f),
                                          fmaxf(d[2], 0.f), fmaxf(d[3], 0.f));
    }

    if constexpr (STAGE == 4) {
        stageW(Wc2, 64 * 64); __syncthreads();
        float d[4] = {0.f, 0.f, 0.f, 0.f};
        for (int k = 0; k < 64; ++k) {
            float cv = Crow[k];
            const float* w = &sW[k * 64 + cc0];
            d[0] = fmaf(cv, w[0], d[0]); d[1] = fmaf(cv, w[1], d[1]);
            d[2] = fmaf(cv, w[2], d[2]); d[3] = fmaf(cv, w[3], d[3]);
        }
        float4 zv = *(const float4*)&zb[orow];
        float4 hv = *(const float4*)&hf[orow];
        float cg0[4] = {ftanh(d[0]), ftanh(d[1]), ftanh(d[2]), ftanh(d[3])};
        float zz[4] = {zv.x, zv.y, zv.z, zv.w};
        float hh[4] = {hv.x, hv.y, hv.z, hv.w};
        float hn[4];
        #pragma unroll
        for (int j = 0; j < 4; ++j) {
            float t1 = __fmul_rn(zz[j], hh[j]);
            float om = __fsub_rn(1.0f, zz[j]);
            float t2 = __fmul_rn(om, cg0[j]);
            hn[j] = __fadd_rn(t1, t2);
        }
        *(float4*)&hf[orow] = make_float4(hn[0], hn[1], hn[2], hn[3]);
        *(float4*)&out[((size_t)(b * T_ + t) * N_ + m0 + rr) * 64 + cc0] =
            make_float4(hn[0], hn[1], hn[2], hn[3]);
    }
    (void)v1;
}

// ================= launch =================

extern "C" void kernel_launch(void* const* d_in, const int* in_sizes, int n_in,
                              void* d_out, int out_size, void* d_ws, size_t ws_size,
                              hipStream_t stream) {
    (void)in_sizes; (void)n_in; (void)out_size; (void)ws_size;
    const float* x    = (const float*)d_in[0];
    const float* e    = (const float*)d_in[1];
    const float* fc_w = (const float*)d_in[2];
    const float* fc_b = (const float*)d_in[3];
    const float* Wz1  = (const float*)d_in[4];
    const float* Wz2  = (const float*)d_in[5];
    const float* Wr1  = (const float*)d_in[6];
    const float* Wr2  = (const float*)d_in[7];
    const float* Wc1  = (const float*)d_in[8];
    const float* Wc2  = (const float*)d_in[9];
    float* out = (float*)d_out;

    char* p = (char*)d_ws;
    auto alloc = [&](size_t bytes) { char* r = p; p += (bytes + 255) & ~(size_t)255; return r; };
    const size_t HSZ = (size_t)B_ * 64 * N_ * 4;
    float* bufXP = (float*)alloc((size_t)B_ * T_ * 64 * N_ * 4);
    float* UX    = (float*)alloc((size_t)B_ * T_ * N_ * 64 * 4);
    float* hT  = (float*)alloc(HSZ);
    float* hzT = (float*)alloc(HSZ);
    float* hrT = (float*)alloc(HSZ);
    float* rhT = (float*)alloc(HSZ);
    float* hcT = (float*)alloc(HSZ);
    unsigned* bars = (unsigned*)alloc(4 * 64 * sizeof(unsigned));

    xpT_kernel<<<dim3(8, B_ * T_), 256, 0, stream>>>(x, fc_w, fc_b, bufXP);
    ux_kernel<<<dim3(64, B_ * T_), 256, 0, stream>>>(e, bufXP, UX);
    hipMemsetAsync(hT, 0, HSZ, stream);
    hipMemsetAsync(bars, 0, 4 * 64 * sizeof(unsigned), stream);

    void* args[] = {(void*)&e, (void*)&UX,
                    (void*)&Wz1, (void*)&Wz2, (void*)&Wr1, (void*)&Wr2,
                    (void*)&Wc1, (void*)&Wc2,
                    (void*)&hT, (void*)&hzT, (void*)&hrT, (void*)&rhT, (void*)&hcT,
                    (void*)&bars, (void*)&out};
    hipError_t err = hipLaunchCooperativeKernel(reinterpret_cast<void*>(egcn_kernel),
                                                dim3(128), dim3(512), args, 0, stream);

    if (err != hipSuccess) {
        // fallback: proven R4 multi-launch path (buffers aliased onto UX region)
        float* b0 = UX;
        float* b1 = UX + 1 * (HSZ / 4);
        float* b2 = UX + 2 * (HSZ / 4);
        float* b3 = UX + 3 * (HSZ / 4);
        float* b4 = UX + 4 * (HSZ / 4);
        float* b5 = UX + 5 * (HSZ / 4);
        float* b6 = UX + 6 * (HSZ / 4);
        hipMemsetAsync(b0, 0, HSZ, stream);
        xp_row_kernel<<<dim3(B_ * T_), 256, 0, stream>>>(x, fc_w, fc_b, bufXP);
        dim3 grid(N_ / 16, B_);
        for (int t = 0; t < T_; ++t) {
            stage_kernel<1><<<grid, 256, 0, stream>>>(e, t, bufXP, Wz1, Wz2, Wr1, Wr2, Wc1, Wc2,
                                                      b0, b1, b2, b3, b4, b5, b6, out);
            stage_kernel<2><<<grid, 256, 0, stream>>>(e, t, bufXP, Wz1, Wz2, Wr1, Wr2, Wc1, Wc2,
                                                      b0, b1, b2, b3, b4, b5, b6, out);
            stage_kernel<3><<<grid, 256, 0, stream>>>(e, t, bufXP, Wz1, Wz2, Wr1, Wr2, Wc1, Wc2,
                                                      b0, b1, b2, b3, b4, b5, b6, out);
            stage_kernel<4><<<grid, 256, 0, stream>>>(e, t, bufXP, Wz1, Wz2, Wr1, Wr2, Wc1, Wc2,
                                                      b0, b1, b2, b3, b4, b5, b6, out);
        }
    }
}

// Round 9
// 2282.057 us; speedup vs baseline: 2.4868x; 2.4868x over previous
//
#include <hip/hip_runtime.h>
#include <cstdint>
#include <cstddef>

#define B_ 4
#define T_ 24
#define N_ 512

// gate nonlinearities: evaluate in f64, round once to f32 (R4-proven numerics)
__device__ __forceinline__ float fsig(float x)  { return (float)(1.0 / (1.0 + exp(-(double)x))); }
__device__ __forceinline__ float ftanh(float x) { return (float)tanh((double)x); }

// 16-slot XOR swizzle for [F][64] LDS tiles (R7-proven)
__device__ __forceinline__ int swz16(int f) { return (((f & 15) ^ ((f >> 4) & 15)) << 2); }

// ================= PRECOMPUTE (parallel, recurrence-free) =================

// xp = relu(x @ fc_w + fc_b), stored feature-major xpT[bt][f][node]
__global__ __launch_bounds__(256) void xpT_kernel(const float* __restrict__ x,
                                                  const float* __restrict__ fc_w,
                                                  const float* __restrict__ fc_b,
                                                  float* __restrict__ xpT) {
    __shared__ __align__(16) float sX[64 * 68];
    __shared__ __align__(16) float sW[64 * 64];
    __shared__ float sB[64];
    const int bt = blockIdx.y;
    const int n0 = blockIdx.x * 64;
    const int tid = threadIdx.x;
    for (int i = tid * 4; i < 4096; i += 1024)
        *(float4*)&sW[i] = *(const float4*)&fc_w[i];
    if (tid < 64) sB[tid] = fc_b[tid];
    {
        int r = tid >> 2, kq = (tid & 3) * 16;
        const float* p = x + ((size_t)bt * N_ + n0 + r) * 64 + kq;
        #pragma unroll
        for (int j = 0; j < 4; ++j)
            *(float4*)&sX[r * 68 + kq + j * 4] = *(const float4*)(p + j * 4);
    }
    __syncthreads();
    const int f = tid & 63, ng = tid >> 6;
    float d[16];
    #pragma unroll
    for (int j = 0; j < 16; ++j) d[j] = 0.f;
    for (int k = 0; k < 64; ++k) {
        float w = sW[k * 64 + f];
        #pragma unroll
        for (int j = 0; j < 16; ++j)
            d[j] = fmaf(sX[(ng * 16 + j) * 68 + k], w, d[j]);
    }
    const float bias = sB[f];
    float* o = xpT + ((size_t)bt * 64 + f) * N_ + n0 + ng * 16;
    #pragma unroll
    for (int j = 0; j < 16; ++j)
        o[j] = fmaxf(__fadd_rn(d[j], bias), 0.f);
}

// UX[bt][node][64] = (A_bt @ xp_bt)
__global__ __launch_bounds__(256) void ux_kernel(const float* __restrict__ e,
                                                 const float* __restrict__ xpT,
                                                 float* __restrict__ UX) {
    __shared__ __align__(16) float sA[8 * N_];
    __shared__ __align__(16) float sVT[2 * 4096];
    const int bt = blockIdx.y;
    const int m0 = blockIdx.x * 8;
    const int tid = threadIdx.x;
    {
        const int r = tid >> 5, seg = (tid & 31) * 16;
        const float* src = e + ((size_t)bt * N_ + m0 + r) * N_ + seg;
        float* dst = sA + r * N_ + seg;
        #pragma unroll
        for (int j = 0; j < 4; ++j)
            *(float4*)(dst + j * 4) = *(const float4*)(src + j * 4);
    }
    const float* s0 = xpT + (size_t)bt * 64 * N_;
    auto stage64 = [&](float* dst, int k0) {
        const int f = tid >> 2, q = tid & 3;
        const int sw = swz16(f);
        const float* src = s0 + (size_t)f * N_ + k0;
        #pragma unroll
        for (int j = 0; j < 4; ++j) {
            int k = q * 16 + j * 4;
            *(float4*)&dst[f * 64 + (k ^ sw)] = *(const float4*)(src + k);
        }
    };
    stage64(sVT, 0);
    __syncthreads();
    const int r = tid >> 5, cgi = tid & 31;
    const int c0 = 2 * cgi, c1 = c0 + 1;
    const int sw0 = swz16(c0), sw1 = swz16(c1);
    float a0 = 0.f, a1 = 0.f;
    for (int kb = 0; kb < 8; ++kb) {
        const float* cur = sVT + (kb & 1) * 4096;
        if (kb < 7) stage64(sVT + ((kb + 1) & 1) * 4096, (kb + 1) * 64);
        const float* A0 = sA + r * N_ + kb * 64;
        const float* V0 = cur + c0 * 64;
        const float* V1 = cur + c1 * 64;
        #pragma unroll
        for (int kg = 0; kg < 16; ++kg) {
            int k = kg * 4;
            float4 x = *(const float4*)(A0 + k);
            float4 v0 = *(const float4*)(V0 + (k ^ sw0));
            float4 v1 = *(const float4*)(V1 + (k ^ sw1));
            a0 = fmaf(x.x, v0.x, a0); a0 = fmaf(x.y, v0.y, a0);
            a0 = fmaf(x.z, v0.z, a0); a0 = fmaf(x.w, v0.w, a0);
            a1 = fmaf(x.x, v1.x, a1); a1 = fmaf(x.y, v1.y, a1);
            a1 = fmaf(x.z, v1.z, a1); a1 = fmaf(x.w, v1.w, a1);
        }
        __syncthreads();
    }
    *(float2*)&UX[((size_t)bt * N_ + m0 + r) * 64 + c0] = make_float2(a0, a1);
}

// ================= STAGE KERNELS (multi-launch, BM=8, 256 blocks, 256 thr) =================
// S1: C = A@h;        hz = relu([UX|C]@Wz1); hr = relu([UX|C]@Wr1)
// S2: C = A@[hz|hr];  z = sig(C_z@Wz2) -> zT; rh = sig(C_r@Wr2)*h
// S3: C = A@rh;       hc = relu(UX@Wc1_top + C@Wc1_bot)
// S4: C = A@hc;       c = tanh(C@Wc2); hn = z*h + (1-z)*c -> hT, out
template <int STAGE>
__global__ __launch_bounds__(256) void stage9_kernel(
    const float* __restrict__ e, int t,
    const float* __restrict__ UX,
    const float* __restrict__ Wz1, const float* __restrict__ Wz2,
    const float* __restrict__ Wr1, const float* __restrict__ Wr2,
    const float* __restrict__ Wc1, const float* __restrict__ Wc2,
    float* __restrict__ hT, float* __restrict__ hzT, float* __restrict__ hrT,
    float* __restrict__ zT, float* __restrict__ rhT, float* __restrict__ hcT,
    float* __restrict__ out)
{
    constexpr int F = (STAGE == 2) ? 128 : 64;
    __shared__ __align__(16) float sA[8 * 512];          // 16 KB
    __shared__ __align__(16) float sV[2 * F * 64];       // 64 KB (F=128) / 32 KB
    __shared__ __align__(16) float sC[8 * 132];
    __shared__ __align__(16) float sUX[8 * 68];

    const int b = blockIdx.y;
    const int m0 = blockIdx.x * 8;
    const int tid = threadIdx.x;
    const int bt = b * T_ + t;

    const float* Ab = e + ((size_t)bt * N_ + m0) * N_;

    const float* s0;
    const float* s1 = nullptr;
    if (STAGE == 1)      { s0 = hT  + (size_t)b * 64 * N_; }
    else if (STAGE == 2) { s0 = hzT + (size_t)b * 64 * N_; s1 = hrT + (size_t)b * 64 * N_; }
    else if (STAGE == 3) { s0 = rhT + (size_t)b * 64 * N_; }
    else                 { s0 = hcT + (size_t)b * 64 * N_; }

    {   // stage A rows [8][512]
        const int r = tid >> 5, seg = (tid & 31) * 16;
        const float* src = Ab + (size_t)r * N_ + seg;
        float* dst = sA + r * 512 + seg;
        #pragma unroll
        for (int j = 0; j < 4; ++j)
            *(float4*)(dst + j * 4) = *(const float4*)(src + j * 4);
    }
    if constexpr (STAGE == 1 || STAGE == 3) {
        if (tid < 128) {    // stage UX tile [8][64]
            const int n = tid >> 4, q = (tid & 15) * 4;
            *(float4*)&sUX[n * 68 + q] =
                *(const float4*)&UX[((size_t)bt * N_ + m0 + n) * 64 + q];
        }
    }

    auto stageV = [&](float* dst, int kt) {
        if constexpr (F == 128) {
            const int f = tid >> 1, h = tid & 1;
            const float* src = ((f < 64) ? (s0 + (size_t)f * N_)
                                         : (s1 + (size_t)(f - 64) * N_)) + kt * 64 + h * 32;
            const int sw = swz16(f);
            #pragma unroll
            for (int j = 0; j < 8; ++j)
                *(float4*)&dst[f * 64 + ((h * 32 + j * 4) ^ sw)] = *(const float4*)(src + j * 4);
        } else {
            const int f = tid >> 2, q = tid & 3;
            const float* src = s0 + (size_t)f * N_ + kt * 64 + q * 16;
            const int sw = swz16(f);
            #pragma unroll
            for (int j = 0; j < 4; ++j)
                *(float4*)&dst[f * 64 + ((q * 16 + j * 4) ^ sw)] = *(const float4*)(src + j * 4);
        }
    };

    // ---- conv: C = A @ V, double-buffered, strict ascending-k fmaf chains ----
    constexpr int RPT = (F == 128) ? 4 : 2;
    const int c = tid & (F - 1);
    const int rg = (F == 128) ? (tid >> 7) : (tid >> 6);
    const int swc = swz16(c);
    float acc[RPT];
    #pragma unroll
    for (int i = 0; i < RPT; ++i) acc[i] = 0.f;

    stageV(sV, 0);
    __syncthreads();
    for (int kb = 0; kb < 8; ++kb) {
        if (kb < 7) stageV(sV + ((kb + 1) & 1) * (F * 64), kb + 1);
        const float* buf = sV + (kb & 1) * (F * 64);
        #pragma unroll
        for (int kg = 0; kg < 16; ++kg) {
            const int k = kg * 4;
            float4 v = *(const float4*)&buf[c * 64 + (k ^ swc)];
            #pragma unroll
            for (int i = 0; i < RPT; ++i) {
                float4 x = *(const float4*)&sA[(rg * RPT + i) * 512 + kb * 64 + k];
                acc[i] = fmaf(x.x, v.x, acc[i]);
                acc[i] = fmaf(x.y, v.y, acc[i]);
                acc[i] = fmaf(x.z, v.z, acc[i]);
                acc[i] = fmaf(x.w, v.w, acc[i]);
            }
        }
        __syncthreads();
    }
    #pragma unroll
    for (int i = 0; i < RPT; ++i)
        sC[(rg * RPT + i) * 132 + c] = acc[i];
    __syncthreads();

    // ---- epilogues (weights straight from L2, f-coalesced) ----
    if constexpr (STAGE == 1) {
        const int sel = tid >> 7, f = tid & 63, ng = (tid >> 6) & 1, n0 = ng * 4;
        const float* W = sel ? Wr1 : Wz1;
        float d[4] = {0.f, 0.f, 0.f, 0.f};
        #pragma unroll 4
        for (int k = 0; k < 64; ++k) {
            float w = W[k * 64 + f];
            #pragma unroll
            for (int j = 0; j < 4; ++j) d[j] = fmaf(sUX[(n0 + j) * 68 + k], w, d[j]);
        }
        #pragma unroll 4
        for (int k = 0; k < 64; ++k) {
            float w = W[(64 + k) * 64 + f];
            #pragma unroll
            for (int j = 0; j < 4; ++j) d[j] = fmaf(sC[(n0 + j) * 132 + k], w, d[j]);
        }
        float* dstT = (sel ? hrT : hzT) + (size_t)b * 64 * N_;
        *(float4*)(dstT + (size_t)f * N_ + m0 + n0) =
            make_float4(fmaxf(d[0], 0.f), fmaxf(d[1], 0.f), fmaxf(d[2], 0.f), fmaxf(d[3], 0.f));
    }

    if constexpr (STAGE == 2) {
        const int sel = tid >> 7, f = tid & 63, ng = (tid >> 6) & 1, n0 = ng * 4;
        const float* W = sel ? Wr2 : Wz2;
        float d[4] = {0.f, 0.f, 0.f, 0.f};
        #pragma unroll 4
        for (int k = 0; k < 64; ++k) {
            float w = W[k * 64 + f];
            #pragma unroll
            for (int j = 0; j < 4; ++j) d[j] = fmaf(sC[(n0 + j) * 132 + sel * 64 + k], w, d[j]);
        }
        if (!sel) {
            *(float4*)(zT + ((size_t)b * 64 + f) * N_ + m0 + n0) =
                make_float4(fsig(d[0]), fsig(d[1]), fsig(d[2]), fsig(d[3]));
        } else {
            float4 h4 = *(const float4*)(hT + ((size_t)b * 64 + f) * N_ + m0 + n0);
            *(float4*)(rhT + ((size_t)b * 64 + f) * N_ + m0 + n0) =
                make_float4(__fmul_rn(fsig(d[0]), h4.x), __fmul_rn(fsig(d[1]), h4.y),
                            __fmul_rn(fsig(d[2]), h4.z), __fmul_rn(fsig(d[3]), h4.w));
        }
    }

    if constexpr (STAGE == 3) {
        const int f = tid & 63, ng = tid >> 6, n0 = ng * 2;
        float d[2] = {0.f, 0.f};
        #pragma unroll 4
        for (int k = 0; k < 64; ++k) {
            float w = Wc1[k * 64 + f];
            d[0] = fmaf(sUX[(n0 + 0) * 68 + k], w, d[0]);
            d[1] = fmaf(sUX[(n0 + 1) * 68 + k], w, d[1]);
        }
        #pragma unroll 4
        for (int k = 0; k < 64; ++k) {
            float w = Wc1[(64 + k) * 64 + f];
            d[0] = fmaf(sC[(n0 + 0) * 132 + k], w, d[0]);
            d[1] = fmaf(sC[(n0 + 1) * 132 + k], w, d[1]);
        }
        *(float2*)(hcT + ((size_t)b * 64 + f) * N_ + m0 + n0) =
            make_float2(fmaxf(d[0], 0.f), fmaxf(d[1], 0.f));
    }

    if constexpr (STAGE == 4) {
        const int f = tid & 63, ng = tid >> 6, n0 = ng * 2;
        float d[2] = {0.f, 0.f};
        #pragma unroll 4
        for (int k = 0; k < 64; ++k) {
            float w = Wc2[k * 64 + f];
            d[0] = fmaf(sC[(n0 + 0) * 132 + k], w, d[0]);
            d[1] = fmaf(sC[(n0 + 1) * 132 + k], w, d[1]);
        }
        float c0 = ftanh(d[0]), c1 = ftanh(d[1]);
        float* hp = hT + ((size_t)b * 64 + f) * N_ + m0 + n0;
        float2 h2 = *(const float2*)hp;
        float2 z2 = *(const float2*)(zT + ((size_t)b * 64 + f) * N_ + m0 + n0);
        float hn0 = __fadd_rn(__fmul_rn(z2.x, h2.x), __fmul_rn(__fsub_rn(1.f, z2.x), c0));
        float hn1 = __fadd_rn(__fmul_rn(z2.y, h2.y), __fmul_rn(__fsub_rn(1.f, z2.y), c1));
        *(float2*)hp = make_float2(hn0, hn1);
        out[((size_t)bt * N_ + m0 + n0) * 64 + f] = hn0;
        out[((size_t)bt * N_ + m0 + n0 + 1) * 64 + f] = hn1;
    }
    (void)s1;
}

// ================= launch =================

extern "C" void kernel_launch(void* const* d_in, const int* in_sizes, int n_in,
                              void* d_out, int out_size, void* d_ws, size_t ws_size,
                              hipStream_t stream) {
    (void)in_sizes; (void)n_in; (void)out_size; (void)ws_size;
    const float* x    = (const float*)d_in[0];
    const float* e    = (const float*)d_in[1];
    const float* fc_w = (const float*)d_in[2];
    const float* fc_b = (const float*)d_in[3];
    const float* Wz1  = (const float*)d_in[4];
    const float* Wz2  = (const float*)d_in[5];
    const float* Wr1  = (const float*)d_in[6];
    const float* Wr2  = (const float*)d_in[7];
    const float* Wc1  = (const float*)d_in[8];
    const float* Wc2  = (const float*)d_in[9];
    float* out = (float*)d_out;

    char* p = (char*)d_ws;
    auto alloc = [&](size_t bytes) { char* r = p; p += (bytes + 255) & ~(size_t)255; return r; };
    const size_t HSZ = (size_t)B_ * 64 * N_ * 4;
    float* xpT = (float*)alloc((size_t)B_ * T_ * 64 * N_ * 4);
    float* UX  = (float*)alloc((size_t)B_ * T_ * N_ * 64 * 4);
    float* hT  = (float*)alloc(HSZ);
    float* hzT = (float*)alloc(HSZ);
    float* hrT = (float*)alloc(HSZ);
    float* zT  = (float*)alloc(HSZ);
    float* rhT = (float*)alloc(HSZ);
    float* hcT = (float*)alloc(HSZ);

    xpT_kernel<<<dim3(8, B_ * T_), 256, 0, stream>>>(x, fc_w, fc_b, xpT);
    ux_kernel<<<dim3(64, B_ * T_), 256, 0, stream>>>(e, xpT, UX);
    hipMemsetAsync(hT, 0, HSZ, stream);

    dim3 grid(N_ / 8, B_);
    for (int t = 0; t < T_; ++t) {
        stage9_kernel<1><<<grid, 256, 0, stream>>>(e, t, UX, Wz1, Wz2, Wr1, Wr2, Wc1, Wc2,
                                                   hT, hzT, hrT, zT, rhT, hcT, out);
        stage9_kernel<2><<<grid, 256, 0, stream>>>(e, t, UX, Wz1, Wz2, Wr1, Wr2, Wc1, Wc2,
                                                   hT, hzT, hrT, zT, rhT, hcT, out);
        stage9_kernel<3><<<grid, 256, 0, stream>>>(e, t, UX, Wz1, Wz2, Wr1, Wr2, Wc1, Wc2,
                                                   hT, hzT, hrT, zT, rhT, hcT, out);
        stage9_kernel<4><<<grid, 256, 0, stream>>>(e, t, UX, Wz1, Wz2, Wr1, Wr2, Wc1, Wc2,
                                                   hT, hzT, hrT, zT, rhT, hcT, out);
    }
}